// Round 15
// baseline (128.218 us; speedup 1.0000x reference)
//
#include <hip/hip_runtime.h>
#include <math.h>

// Problem constants (from reference):
constexpr int Bn = 1024;
constexpr int S  = 512;
constexpr int H  = 768;
constexpr int D1 = 128;
constexpr int HV = H / 4;     // 192 float4 per feature row
constexpr int NH = 512;       // cls-head blocks fused into launch 1

// ws layout (floats):
//   gp [2][Bn][768]  — span-mean partials (even/odd rows), pre-scaled by 1/len
//   P  [6][Bn][D1]   — partial h dots: [0,1]=CLS 384-chunks, [2..5]=CRC 192-chunks
//   ticket [256] uint — last-block tickets (mod-4 trick: NO reset needed)

// Launch 1 (R14-exact): blocks [0,NH) = CLS-half head; [NH,NH+2048) = pool.
__global__ __launch_bounds__(256) void fused_pool_clshead(
    const float* __restrict__ feat, const int* __restrict__ start,
    const int* __restrict__ endp, float* __restrict__ gp,
    const float* __restrict__ W1, float* __restrict__ P) {
  __shared__ float g[4][384];        // 6 KB (head path only)
  __shared__ float part[2][4][D1];   // 4 KB

  const int t = threadIdx.x;

  if (blockIdx.x < NH) {
    // ---- CLS-half head: chunk c in {0,1}, 4 examples ----
    const int c = blockIdx.x & 1;
    const int e0 = (blockIdx.x >> 1) * 4;
    const int dglob0 = c * 384;

    for (int i = t; i < 384; i += 256) {
      const int e = i / 96;          // 96 float4 per example-chunk
      const int j = i % 96;
      float4 v = *reinterpret_cast<const float4*>(
          feat + (size_t)(e0 + e) * S * H + dglob0 + j * 4);
      reinterpret_cast<float4*>(&g[e][0])[j] = v;
    }
    __syncthreads();

    const int k = t & (D1 - 1);
    const int sub = t >> 7;
    const int gofs = sub * 192;
    const float* Wc = W1 + (size_t)(dglob0 + gofs) * D1 + k;

    float a0 = 0.f, a1 = 0.f, a2 = 0.f, a3 = 0.f;
    #pragma unroll 4
    for (int d = 0; d < 192; d += 4) {
      float w0 = Wc[(size_t)(d + 0) * D1];
      float w1 = Wc[(size_t)(d + 1) * D1];
      float w2 = Wc[(size_t)(d + 2) * D1];
      float w3 = Wc[(size_t)(d + 3) * D1];
      float4 g0 = *reinterpret_cast<const float4*>(&g[0][gofs + d]);
      float4 g1 = *reinterpret_cast<const float4*>(&g[1][gofs + d]);
      float4 g2 = *reinterpret_cast<const float4*>(&g[2][gofs + d]);
      float4 g3 = *reinterpret_cast<const float4*>(&g[3][gofs + d]);
      a0 += g0.x * w0 + g0.y * w1 + g0.z * w2 + g0.w * w3;
      a1 += g1.x * w0 + g1.y * w1 + g1.z * w2 + g1.w * w3;
      a2 += g2.x * w0 + g2.y * w1 + g2.z * w2 + g2.w * w3;
      a3 += g3.x * w0 + g3.y * w1 + g3.z * w2 + g3.w * w3;
    }
    part[sub][0][k] = a0;
    part[sub][1][k] = a1;
    part[sub][2][k] = a2;
    part[sub][3][k] = a3;
    __syncthreads();

    if (t < D1) {
      #pragma unroll
      for (int e = 0; e < 4; ++e) {
        P[((size_t)c * Bn + (e0 + e)) * D1 + t] = part[0][e][t] + part[1][e][t];
      }
    }
    return;
  }

  // ---- pool: R2-exact span mean-pool ----
  if (t >= 192) return;              // wave 3 retires immediately
  const int bb = blockIdx.x - NH;
  const int b = bb >> 1;
  const int p = bb & 1;
  const float4* base = reinterpret_cast<const float4*>(feat) + (size_t)b * (S * HV);

  const int s0 = start[b];
  const int s1 = endp[b];
  float4 a0{0,0,0,0}, a1{0,0,0,0}, a2{0,0,0,0}, a3{0,0,0,0};
  int s = s0 + p;
  for (; s + 6 < s1; s += 8) {
    float4 v0 = base[(size_t)(s    ) * HV + t];
    float4 v1 = base[(size_t)(s + 2) * HV + t];
    float4 v2 = base[(size_t)(s + 4) * HV + t];
    float4 v3 = base[(size_t)(s + 6) * HV + t];
    a0.x += v0.x; a0.y += v0.y; a0.z += v0.z; a0.w += v0.w;
    a1.x += v1.x; a1.y += v1.y; a1.z += v1.z; a1.w += v1.w;
    a2.x += v2.x; a2.y += v2.y; a2.z += v2.z; a2.w += v2.w;
    a3.x += v3.x; a3.y += v3.y; a3.z += v3.z; a3.w += v3.w;
  }
  for (; s < s1; s += 2) {
    float4 v = base[(size_t)s * HV + t];
    a0.x += v.x; a0.y += v.y; a0.z += v.z; a0.w += v.w;
  }
  const float inv = 1.0f / (float)(s1 - s0);
  float4 r;
  r.x = ((a0.x + a1.x) + (a2.x + a3.x)) * inv;
  r.y = ((a0.y + a1.y) + (a2.y + a3.y)) * inv;
  r.z = ((a0.z + a1.z) + (a2.z + a3.z)) * inv;
  r.w = ((a0.w + a1.w) + (a2.w + a3.w)) * inv;
  reinterpret_cast<float4*>(gp)[((size_t)p * Bn + b) * HV + t] = r;
}

// Launch 2: CRC head (R14-exact inner) + last-block finalize.
// Block = 4 examples x 192-row CRC chunk cc in {0..3}; grid 1024 x 256 thr.
// The 4th-arriving block per example-group (mod-4 ticket, no reset needed)
// runs the finalize for its 4 examples — no third launch, no spinning.
__global__ __launch_bounds__(256) void crc_head_fin(
    const float* __restrict__ gp, const float* __restrict__ W1,
    float* __restrict__ P, const float* __restrict__ b1,
    const float* __restrict__ W2, const float* __restrict__ b2,
    unsigned* __restrict__ ticket, float* __restrict__ out) {
  __shared__ float g[4][192];        // 3 KB: 4 examples' 192-row chunk
  __shared__ float part[2][4][D1];   // 4 KB
  __shared__ int winner;

  const int t = threadIdx.x;
  const int cc = blockIdx.x & 3;     // CRC chunk 0..3
  const int eg = blockIdx.x >> 2;
  const int e0 = eg * 4;
  const int dd0 = cc * 192;          // offset within CRC half

  // Stage g: crc chunk = gp0 + gp1, 4 examples x 48 float4
  for (int i = t; i < 192; i += 256) {
    const int e = i / 48;
    const int j = i % 48;
    const float* b0 = gp + (size_t)(e0 + e) * H + dd0;
    float4 u0 = reinterpret_cast<const float4*>(b0)[j];
    float4 u1 = reinterpret_cast<const float4*>(b0 + (size_t)Bn * H)[j];
    float4 v;
    v.x = u0.x + u1.x; v.y = u0.y + u1.y;
    v.z = u0.z + u1.z; v.w = u0.w + u1.w;
    reinterpret_cast<float4*>(&g[e][0])[j] = v;
  }
  __syncthreads();

  const int k = t & (D1 - 1);
  const int sub = t >> 7;            // 96-row half of the chunk
  const int gofs = sub * 96;
  const float* Wc = W1 + (size_t)(H + dd0 + gofs) * D1 + k;

  float a0 = 0.f, a1 = 0.f, a2 = 0.f, a3 = 0.f;
  #pragma unroll 4
  for (int d = 0; d < 96; d += 4) {
    float w0 = Wc[(size_t)(d + 0) * D1];
    float w1 = Wc[(size_t)(d + 1) * D1];
    float w2 = Wc[(size_t)(d + 2) * D1];
    float w3 = Wc[(size_t)(d + 3) * D1];
    float4 g0 = *reinterpret_cast<const float4*>(&g[0][gofs + d]);
    float4 g1 = *reinterpret_cast<const float4*>(&g[1][gofs + d]);
    float4 g2 = *reinterpret_cast<const float4*>(&g[2][gofs + d]);
    float4 g3 = *reinterpret_cast<const float4*>(&g[3][gofs + d]);
    a0 += g0.x * w0 + g0.y * w1 + g0.z * w2 + g0.w * w3;
    a1 += g1.x * w0 + g1.y * w1 + g1.z * w2 + g1.w * w3;
    a2 += g2.x * w0 + g2.y * w1 + g2.z * w2 + g2.w * w3;
    a3 += g3.x * w0 + g3.y * w1 + g3.z * w2 + g3.w * w3;
  }
  part[sub][0][k] = a0;
  part[sub][1][k] = a1;
  part[sub][2][k] = a2;
  part[sub][3][k] = a3;
  __syncthreads();

  if (t < D1) {
    #pragma unroll
    for (int e = 0; e < 4; ++e) {
      P[((size_t)(2 + cc) * Bn + (e0 + e)) * D1 + t] =
          part[0][e][t] + part[1][e][t];
    }
  }
  // Publish partials, then take a ticket; 4th arrival finalizes.
  __threadfence();                   // device-scope release of P stores
  __syncthreads();
  if (t == 0) {
    unsigned old = __hip_atomic_fetch_add(&ticket[eg], 1u,
                                          __ATOMIC_ACQ_REL,
                                          __HIP_MEMORY_SCOPE_AGENT);
    winner = ((old & 3u) == 3u);     // exactly one of any 4 consecutive ints
  }
  __syncthreads();
  if (!winner) return;

  // ---- finalize (R14-exact body): wave w owns example e0+w ----
  {
    const int w = t >> 6, l = t & 63;
    const int e = e0 + w;
    const int k0 = l, k1 = l + 64;
    float h0 = b1[k0], h1 = b1[k1];
    #pragma unroll
    for (int c = 0; c < 6; ++c) {
      h0 += P[((size_t)c * Bn + e) * D1 + k0];
      h1 += P[((size_t)c * Bn + e) * D1 + k1];
    }
    h0 = fmaxf(h0, 0.f); h1 = fmaxf(h1, 0.f);
    float v = h0 * W2[k0] + h1 * W2[k1];
    #pragma unroll
    for (int off = 32; off > 0; off >>= 1) v += __shfl_down(v, off);
    if (l == 0) out[e] = 1.0f / (1.0f + expf(-(v + b2[0])));
  }
}

extern "C" void kernel_launch(void* const* d_in, const int* in_sizes, int n_in,
                              void* d_out, int out_size, void* d_ws, size_t ws_size,
                              hipStream_t stream) {
  const float* feat = (const float*)d_in[0];   // [B,S,H] fp32
  const int* start  = (const int*)d_in[1];     // [B]
  const int* endp   = (const int*)d_in[2];     // [B]
  const float* W1   = (const float*)d_in[3];   // [2H,D1]
  const float* b1   = (const float*)d_in[4];   // [D1]
  const float* W2   = (const float*)d_in[5];   // [D1,1]
  const float* b2   = (const float*)d_in[6];   // [1]
  float* out = (float*)d_out;                  // [B]

  float* wsf = (float*)d_ws;
  float* gp  = wsf;                            // [2][Bn][768]
  float* P   = gp + (size_t)2 * Bn * H;        // [6][Bn][D1]
  unsigned* ticket = (unsigned*)(P + (size_t)6 * Bn * D1);  // [256]

  hipLaunchKernelGGL(fused_pool_clshead, dim3(NH + Bn * 2), dim3(256), 0,
                     stream, feat, start, endp, gp, W1, P);
  hipLaunchKernelGGL(crc_head_fin, dim3(Bn), dim3(256), 0, stream,
                     gp, W1, P, b1, W2, b2, ticket, out);
}

// Round 16
// 32.853 us; speedup vs baseline: 3.9028x; 3.9028x over previous
//
#include <hip/hip_runtime.h>
#include <math.h>

// Problem constants (from reference):
constexpr int Bn = 1024;
constexpr int S  = 512;
constexpr int H  = 768;
constexpr int D1 = 128;
constexpr int HV = H / 4;     // 192 float4 per feature row
constexpr int NH = 512;       // cls-head blocks (first in launch-1 grid)

// ws layout (floats):
//   gp [Bn][768] — final span means (ONE plane)
//   P  [6][Bn][D1] — partial h dots: [0,1]=CLS 384-chunks, [2..5]=CRC 192-chunks

// Launch 1: blocks [0,NH) = CLS-half head (R14-exact); [NH,NH+1024) = pool.
// Pool block = 1 example, 4 waves, wave w owns rows s0+w (stride 4);
// lane owns 3 float4 cols; LDS cross-wave reduce -> single gp plane.
__global__ __launch_bounds__(256) void fused_pool_clshead(
    const float* __restrict__ feat, const int* __restrict__ start,
    const int* __restrict__ endp, float* __restrict__ gp,
    const float* __restrict__ W1, float* __restrict__ P) {
  __shared__ __align__(16) char smem[12288];   // union: cls 10 KB / pool 12 KB

  const int t = threadIdx.x;

  if (blockIdx.x < NH) {
    // ---- CLS-half head (R14-exact): chunk c in {0,1}, 4 examples ----
    float (*g)[384] = reinterpret_cast<float (*)[384]>(smem);
    float (*part)[4][D1] = reinterpret_cast<float (*)[4][D1]>(smem + 6144);

    const int c = blockIdx.x & 1;
    const int e0 = (blockIdx.x >> 1) * 4;
    const int dglob0 = c * 384;

    for (int i = t; i < 384; i += 256) {
      const int e = i / 96;          // 96 float4 per example-chunk
      const int j = i % 96;
      float4 v = *reinterpret_cast<const float4*>(
          feat + (size_t)(e0 + e) * S * H + dglob0 + j * 4);
      reinterpret_cast<float4*>(&g[e][0])[j] = v;
    }
    __syncthreads();

    const int k = t & (D1 - 1);
    const int sub = t >> 7;
    const int gofs = sub * 192;
    const float* Wc = W1 + (size_t)(dglob0 + gofs) * D1 + k;

    float a0 = 0.f, a1 = 0.f, a2 = 0.f, a3 = 0.f;
    #pragma unroll 4
    for (int d = 0; d < 192; d += 4) {
      float w0 = Wc[(size_t)(d + 0) * D1];
      float w1 = Wc[(size_t)(d + 1) * D1];
      float w2 = Wc[(size_t)(d + 2) * D1];
      float w3 = Wc[(size_t)(d + 3) * D1];
      float4 g0 = *reinterpret_cast<const float4*>(&g[0][gofs + d]);
      float4 g1 = *reinterpret_cast<const float4*>(&g[1][gofs + d]);
      float4 g2 = *reinterpret_cast<const float4*>(&g[2][gofs + d]);
      float4 g3 = *reinterpret_cast<const float4*>(&g[3][gofs + d]);
      a0 += g0.x * w0 + g0.y * w1 + g0.z * w2 + g0.w * w3;
      a1 += g1.x * w0 + g1.y * w1 + g1.z * w2 + g1.w * w3;
      a2 += g2.x * w0 + g2.y * w1 + g2.z * w2 + g2.w * w3;
      a3 += g3.x * w0 + g3.y * w1 + g3.z * w2 + g3.w * w3;
    }
    part[sub][0][k] = a0;
    part[sub][1][k] = a1;
    part[sub][2][k] = a2;
    part[sub][3][k] = a3;
    __syncthreads();

    if (t < D1) {
      #pragma unroll
      for (int e = 0; e < 4; ++e) {
        P[((size_t)c * Bn + (e0 + e)) * D1 + t] = part[0][e][t] + part[1][e][t];
      }
    }
    return;
  }

  // ---- pool: 1 example/block, 4 waves, stride-4 rows, LDS reduce ----
  {
    float4 (*pacc)[3][64] = reinterpret_cast<float4 (*)[3][64]>(smem);
    const int b = blockIdx.x - NH;
    const int w = t >> 6;            // wave 0..3
    const int l = t & 63;            // lane
    const float4* base =
        reinterpret_cast<const float4*>(feat) + (size_t)b * (S * HV);

    const int s0 = start[b];
    const int s1 = endp[b];

    float4 c0{0,0,0,0}, c1{0,0,0,0}, c2{0,0,0,0};   // cols l, l+64, l+128
    float4 d0{0,0,0,0}, d1{0,0,0,0}, d2{0,0,0,0};   // second-row accumulators
    int s = s0 + w;
    for (; s + 4 < s1; s += 8) {     // 2 rows x 3 segments = 6 loads in flight
      const float4* r0 = base + (size_t)s * HV;
      const float4* r1 = base + (size_t)(s + 4) * HV;
      float4 u0 = r0[l], u1 = r0[l + 64], u2 = r0[l + 128];
      float4 v0 = r1[l], v1 = r1[l + 64], v2 = r1[l + 128];
      c0.x += u0.x; c0.y += u0.y; c0.z += u0.z; c0.w += u0.w;
      c1.x += u1.x; c1.y += u1.y; c1.z += u1.z; c1.w += u1.w;
      c2.x += u2.x; c2.y += u2.y; c2.z += u2.z; c2.w += u2.w;
      d0.x += v0.x; d0.y += v0.y; d0.z += v0.z; d0.w += v0.w;
      d1.x += v1.x; d1.y += v1.y; d1.z += v1.z; d1.w += v1.w;
      d2.x += v2.x; d2.y += v2.y; d2.z += v2.z; d2.w += v2.w;
    }
    for (; s < s1; s += 4) {
      const float4* r0 = base + (size_t)s * HV;
      float4 u0 = r0[l], u1 = r0[l + 64], u2 = r0[l + 128];
      c0.x += u0.x; c0.y += u0.y; c0.z += u0.z; c0.w += u0.w;
      c1.x += u1.x; c1.y += u1.y; c1.z += u1.z; c1.w += u1.w;
      c2.x += u2.x; c2.y += u2.y; c2.z += u2.z; c2.w += u2.w;
    }
    c0.x += d0.x; c0.y += d0.y; c0.z += d0.z; c0.w += d0.w;
    c1.x += d1.x; c1.y += d1.y; c1.z += d1.z; c1.w += d1.w;
    c2.x += d2.x; c2.y += d2.y; c2.z += d2.z; c2.w += d2.w;
    pacc[w][0][l] = c0;
    pacc[w][1][l] = c1;
    pacc[w][2][l] = c2;
    __syncthreads();

    if (t < 192) {
      const int seg = t >> 6, ln = t & 63;
      float4 a = pacc[0][seg][ln], bb = pacc[1][seg][ln];
      float4 cq = pacc[2][seg][ln], dq = pacc[3][seg][ln];
      const float inv = 1.0f / (float)(s1 - s0);
      float4 r;
      r.x = ((a.x + bb.x) + (cq.x + dq.x)) * inv;
      r.y = ((a.y + bb.y) + (cq.y + dq.y)) * inv;
      r.z = ((a.z + bb.z) + (cq.z + dq.z)) * inv;
      r.w = ((a.w + bb.w) + (cq.w + dq.w)) * inv;
      reinterpret_cast<float4*>(gp)[(size_t)b * HV + t] = r;
    }
  }
}

// Launch 2: CRC head (4-chunk split, grid 1024) — single-plane staging,
// 8-row-deep inner loop (more loads in flight; head is latency-bound, R7).
__global__ __launch_bounds__(256) void crc_head(
    const float* __restrict__ gp, const float* __restrict__ W1,
    float* __restrict__ P) {
  __shared__ float g[4][192];        // 3 KB: 4 examples' 192-row chunk
  __shared__ float part[2][4][D1];   // 4 KB

  const int t = threadIdx.x;
  const int cc = blockIdx.x & 3;     // CRC chunk 0..3
  const int e0 = (blockIdx.x >> 2) * 4;
  const int dd04 = cc * 48;          // chunk offset in float4

  // Stage: 4 examples x 48 float4, one read each (single plane).
  if (t < 192) {
    const int e = t / 48;
    const int j = t % 48;
    float4 v = reinterpret_cast<const float4*>(gp)[(size_t)(e0 + e) * HV + dd04 + j];
    reinterpret_cast<float4*>(&g[e][0])[j] = v;
  }
  __syncthreads();

  const int k = t & (D1 - 1);
  const int sub = t >> 7;            // 96-row half of the chunk
  const int gofs = sub * 96;
  const float* Wc = W1 + (size_t)(H + cc * 192 + gofs) * D1 + k;

  float a0 = 0.f, a1 = 0.f, a2 = 0.f, a3 = 0.f;
  #pragma unroll 2
  for (int d = 0; d < 96; d += 8) {
    float w0 = Wc[(size_t)(d + 0) * D1];
    float w1 = Wc[(size_t)(d + 1) * D1];
    float w2 = Wc[(size_t)(d + 2) * D1];
    float w3 = Wc[(size_t)(d + 3) * D1];
    float w4 = Wc[(size_t)(d + 4) * D1];
    float w5 = Wc[(size_t)(d + 5) * D1];
    float w6 = Wc[(size_t)(d + 6) * D1];
    float w7 = Wc[(size_t)(d + 7) * D1];
    #define ACC8(i)                                                        \
    {                                                                      \
      float4 gA = *reinterpret_cast<const float4*>(&g[i][gofs + d]);       \
      float4 gB = *reinterpret_cast<const float4*>(&g[i][gofs + d + 4]);   \
      a##i += gA.x * w0 + gA.y * w1 + gA.z * w2 + gA.w * w3                \
            + gB.x * w4 + gB.y * w5 + gB.z * w6 + gB.w * w7;               \
    }
    ACC8(0) ACC8(1) ACC8(2) ACC8(3)
    #undef ACC8
  }
  part[sub][0][k] = a0;
  part[sub][1][k] = a1;
  part[sub][2][k] = a2;
  part[sub][3][k] = a3;
  __syncthreads();

  if (t < D1) {
    #pragma unroll
    for (int e = 0; e < 4; ++e) {
      P[((size_t)(2 + cc) * Bn + (e0 + e)) * D1 + t] =
          part[0][e][t] + part[1][e][t];
    }
  }
}

// Launch 3 (R14-exact): combine 6 chunks, relu, W2, sigmoid. 1 wave/example.
__global__ __launch_bounds__(256) void finalize(
    const float* __restrict__ P, const float* __restrict__ b1,
    const float* __restrict__ W2, const float* __restrict__ b2,
    float* __restrict__ out) {
  const int t = threadIdx.x;
  const int w = t >> 6, l = t & 63;
  const int e = blockIdx.x * 4 + w;
  const int k0 = l, k1 = l + 64;
  float h0 = b1[k0], h1 = b1[k1];
  #pragma unroll
  for (int c = 0; c < 6; ++c) {
    h0 += P[((size_t)c * Bn + e) * D1 + k0];
    h1 += P[((size_t)c * Bn + e) * D1 + k1];
  }
  h0 = fmaxf(h0, 0.f); h1 = fmaxf(h1, 0.f);
  float v = h0 * W2[k0] + h1 * W2[k1];
  #pragma unroll
  for (int off = 32; off > 0; off >>= 1) v += __shfl_down(v, off);
  if (l == 0) out[e] = 1.0f / (1.0f + expf(-(v + b2[0])));
}

extern "C" void kernel_launch(void* const* d_in, const int* in_sizes, int n_in,
                              void* d_out, int out_size, void* d_ws, size_t ws_size,
                              hipStream_t stream) {
  const float* feat = (const float*)d_in[0];   // [B,S,H] fp32
  const int* start  = (const int*)d_in[1];     // [B]
  const int* endp   = (const int*)d_in[2];     // [B]
  const float* W1   = (const float*)d_in[3];   // [2H,D1]
  const float* b1   = (const float*)d_in[4];   // [D1]
  const float* W2   = (const float*)d_in[5];   // [D1,1]
  const float* b2   = (const float*)d_in[6];   // [1]
  float* out = (float*)d_out;                  // [B]

  float* wsf = (float*)d_ws;
  float* gp  = wsf;                            // [Bn][768]
  float* P   = gp + (size_t)Bn * H;            // [6][Bn][D1]

  hipLaunchKernelGGL(fused_pool_clshead, dim3(NH + Bn), dim3(256), 0,
                     stream, feat, start, endp, gp, W1, P);
  hipLaunchKernelGGL(crc_head, dim3(Bn), dim3(256), 0, stream, gp, W1, P);
  hipLaunchKernelGGL(finalize, dim3(Bn / 4), dim3(256), 0, stream,
                     P, b1, W2, b2, out);
}